// Round 8
// baseline (28.182 us; speedup 1.0000x reference)
//
#include <hip/hip_runtime.h>

// BatchAllTripletLoss, B=512, E=128, labels in [0,64), MARGIN=1.0, EPS=1e-16.
// SINGLE kernel, 256 blocks = 16x16 grid of 32x32 (anchor x negative) tiles.
//  1) stage At/Bt/labels (coalesced float4)
//  2) per-anchor positive masks via ballots -> plist + prefix offsets
//  3) 2x2 register-blocked dist tile, diff^2 form (no norms phase)
//  4) posd (anchor-positive dists) computed wave-cooperatively:
//     16 lanes/pair, anchor half from LDS At, positive row via COALESCED
//     global float4 reads (4-deep load batching), shfl_xor reduce.
//  5) hinge vs LDS pd; block reduce -> publish partial (atomicExch,
//     different addresses = parallel); residue counter ((old&255)==255,
//     correct for any initial value); last block reduces 256 partials.
// No grid.sync, no same-address atomic storms, deterministic.

#define BSZ 512
#define EDIM 128
#define TS 32
#define NPOS 40

__global__ __launch_bounds__(256) void triplet_one(
    const float* __restrict__ embs,
    const int* __restrict__ labels,
    float* __restrict__ sums,
    float* __restrict__ cnts,
    unsigned int* __restrict__ ctr,
    float* __restrict__ out)
{
    __shared__ float At[TS][EDIM + 4];
    __shared__ float Bt[TS][EDIM + 4];
    __shared__ int   lab[BSZ];
    __shared__ unsigned long long masks[TS][8];
    __shared__ int   plist[TS][NPOS];
    __shared__ float pd[TS][NPOS];
    __shared__ int   npsh[TS];
    __shared__ int   offs[TS + 1];
    __shared__ int   pairRI[TS * NPOS];
    __shared__ float wsum[4];
    __shared__ int   wcnt[4];
    __shared__ int   isLast;
    __shared__ float fsum[4], fcnt[4];

    const int tid = threadIdx.x;
    const int bi = blockIdx.x >> 4, bj = blockIdx.x & 15;
    const int I = bi * TS, J = bj * TS;
    const int wv = tid >> 6, lane = tid & 63;

    // ---- 1) stage tiles + labels ----
#pragma unroll
    for (int q = 0; q < 4; ++q) {
        int idx = tid + 256 * q;
        int r = idx >> 5, k4 = idx & 31;
        float4 va = reinterpret_cast<const float4*>(embs + (size_t)(I + r) * EDIM)[k4];
        *reinterpret_cast<float4*>(&At[r][k4 * 4]) = va;
        float4 vb = reinterpret_cast<const float4*>(embs + (size_t)(J + r) * EDIM)[k4];
        *reinterpret_cast<float4*>(&Bt[r][k4 * 4]) = vb;
    }
    lab[tid]       = labels[tid];
    lab[tid + 256] = labels[tid + 256];
    __syncthreads();

    // ---- 2) positive masks (ballots), plist, offsets, pair map ----
#pragma unroll
    for (int rr = 0; rr < 8; ++rr) {
        int r = wv * 8 + rr;
        int la = lab[I + r];
#pragma unroll
        for (int c = 0; c < 8; ++c) {
            int j = c * 64 + lane;
            unsigned long long m = __ballot(lab[j] == la && j != I + r);
            if (lane == 0) masks[r][c] = m;
        }
    }
    __syncthreads();

    if (tid < TS) {
        int cp = 0;
#pragma unroll
        for (int w = 0; w < 8; ++w) {
            unsigned long long m = masks[tid][w];
            while (m) {
                int b = __builtin_ctzll(m);
                m &= m - 1;
                if (cp < NPOS) plist[tid][cp] = w * 64 + b;
                ++cp;
            }
        }
        npsh[tid] = cp < NPOS ? cp : NPOS;
    }
    __syncthreads();

    if (tid < TS) {
        int o = 0;
        for (int r = 0; r < tid; ++r) o += npsh[r];
        offs[tid] = o;
        if (tid == TS - 1) offs[TS] = o + npsh[tid];
        for (int i = 0; i < npsh[tid]; ++i) pairRI[o + i] = (tid << 16) | i;
    }
    __syncthreads();
    const int total = offs[TS];

    // ---- 3) 2x2 register-blocked dist tile (diff^2) ----
    const int tr = tid >> 4, tc = tid & 15;
    float d00 = 0.f, d01 = 0.f, d10 = 0.f, d11 = 0.f;
#pragma unroll 8
    for (int k = 0; k < EDIM; k += 4) {
        float4 x0 = *reinterpret_cast<float4*>(&At[tr][k]);
        float4 x1 = *reinterpret_cast<float4*>(&At[tr + 16][k]);
        float4 y0 = *reinterpret_cast<float4*>(&Bt[tc][k]);
        float4 y1 = *reinterpret_cast<float4*>(&Bt[tc + 16][k]);
        float u;
        u = x0.x - y0.x; d00 = fmaf(u, u, d00);
        u = x0.y - y0.y; d00 = fmaf(u, u, d00);
        u = x0.z - y0.z; d00 = fmaf(u, u, d00);
        u = x0.w - y0.w; d00 = fmaf(u, u, d00);
        u = x0.x - y1.x; d01 = fmaf(u, u, d01);
        u = x0.y - y1.y; d01 = fmaf(u, u, d01);
        u = x0.z - y1.z; d01 = fmaf(u, u, d01);
        u = x0.w - y1.w; d01 = fmaf(u, u, d01);
        u = x1.x - y0.x; d10 = fmaf(u, u, d10);
        u = x1.y - y0.y; d10 = fmaf(u, u, d10);
        u = x1.z - y0.z; d10 = fmaf(u, u, d10);
        u = x1.w - y0.w; d10 = fmaf(u, u, d10);
        u = x1.x - y1.x; d11 = fmaf(u, u, d11);
        u = x1.y - y1.y; d11 = fmaf(u, u, d11);
        u = x1.z - y1.z; d11 = fmaf(u, u, d11);
        u = x1.w - y1.w; d11 = fmaf(u, u, d11);
    }

    // ---- 4) posd: 16 lanes per pair, coalesced global reads, batch-4 ----
    {
        const int g = lane >> 4, lg = lane & 15;
        const float4* EB = reinterpret_cast<const float4*>(embs);
        const int q0 = wv * 4 + g;
        for (int qb = q0; qb < total; qb += 64) {
            float4 xpv[4][2];
            int rr_[4], ii_[4];
#pragma unroll
            for (int t = 0; t < 4; ++t) {
                int q = qb + t * 16;
                if (q < total) {
                    int ri = pairRI[q];
                    int r = ri >> 16, idx = ri & 0xffff;
                    rr_[t] = r; ii_[t] = idx;
                    const float4* P = EB + (size_t)plist[r][idx] * (EDIM / 4);
                    xpv[t][0] = P[lg * 2];
                    xpv[t][1] = P[lg * 2 + 1];
                } else {
                    rr_[t] = -1; ii_[t] = 0;
                    xpv[t][0] = make_float4(0.f, 0.f, 0.f, 0.f);
                    xpv[t][1] = make_float4(0.f, 0.f, 0.f, 0.f);
                }
            }
#pragma unroll
            for (int t = 0; t < 4; ++t) {
                if (rr_[t] >= 0) {
                    int r = rr_[t], idx = ii_[t];
                    float4 xa0 = *reinterpret_cast<float4*>(&At[r][lg * 8]);
                    float4 xa1 = *reinterpret_cast<float4*>(&At[r][lg * 8 + 4]);
                    float u, acc = 0.f;
                    u = xa0.x - xpv[t][0].x; acc = fmaf(u, u, acc);
                    u = xa0.y - xpv[t][0].y; acc = fmaf(u, u, acc);
                    u = xa0.z - xpv[t][0].z; acc = fmaf(u, u, acc);
                    u = xa0.w - xpv[t][0].w; acc = fmaf(u, u, acc);
                    u = xa1.x - xpv[t][1].x; acc = fmaf(u, u, acc);
                    u = xa1.y - xpv[t][1].y; acc = fmaf(u, u, acc);
                    u = xa1.z - xpv[t][1].z; acc = fmaf(u, u, acc);
                    u = xa1.w - xpv[t][1].w; acc = fmaf(u, u, acc);
                    acc += __shfl_xor(acc, 1);
                    acc += __shfl_xor(acc, 2);
                    acc += __shfl_xor(acc, 4);
                    acc += __shfl_xor(acc, 8);
                    if (lg == 0) pd[r][idx] = acc;
                }
            }
        }
    }
    __syncthreads();

    // ---- 5) hinge vs LDS pd (broadcast reads) ----
    const int la0 = lab[I + tr], la1 = lab[I + tr + 16];
    const int lj0 = lab[J + tc], lj1 = lab[J + tc + 16];
    const int np0 = npsh[tr],    np1 = npsh[tr + 16];

    float s = 0.f;
    int   c = 0;
    if (lj0 != la0) for (int i = 0; i < np0; ++i) { float t = fmaxf(pd[tr][i] - d00 + 1.0f, 0.f); s += t; c += (t > 1e-16f); }
    if (lj1 != la0) for (int i = 0; i < np0; ++i) { float t = fmaxf(pd[tr][i] - d01 + 1.0f, 0.f); s += t; c += (t > 1e-16f); }
    if (lj0 != la1) for (int i = 0; i < np1; ++i) { float t = fmaxf(pd[tr + 16][i] - d10 + 1.0f, 0.f); s += t; c += (t > 1e-16f); }
    if (lj1 != la1) for (int i = 0; i < np1; ++i) { float t = fmaxf(pd[tr + 16][i] - d11 + 1.0f, 0.f); s += t; c += (t > 1e-16f); }

    // ---- block reduction ----
#pragma unroll
    for (int off = 32; off; off >>= 1) {
        s += __shfl_down(s, off);
        c += __shfl_down(c, off);
    }
    if (lane == 0) { wsum[wv] = s; wcnt[wv] = c; }
    __syncthreads();

    // ---- publish + last-block finalize ----
    if (tid == 0) {
        float Sb = wsum[0] + wsum[1] + wsum[2] + wsum[3];
        float Cb = (float)(wcnt[0] + wcnt[1] + wcnt[2] + wcnt[3]);
        atomicExch(&sums[blockIdx.x], Sb);
        atomicExch(&cnts[blockIdx.x], Cb);
        __threadfence();
        unsigned int old = atomicAdd(ctr, 1u);
        isLast = ((old & 255u) == 255u) ? 1 : 0;
    }
    __syncthreads();

    if (isLast) {
        __threadfence();
        float s2 = atomicAdd(&sums[tid], 0.0f);   // device-scope load
        float c2 = atomicAdd(&cnts[tid], 0.0f);
#pragma unroll
        for (int off = 32; off; off >>= 1) {
            s2 += __shfl_down(s2, off);
            c2 += __shfl_down(c2, off);
        }
        if (lane == 0) { fsum[wv] = s2; fcnt[wv] = c2; }
        __syncthreads();
        if (tid == 0) {
            float S = fsum[0] + fsum[1] + fsum[2] + fsum[3];
            float C = fcnt[0] + fcnt[1] + fcnt[2] + fcnt[3];
            out[0] = S / (C + 1e-16f);
        }
    }
}

extern "C" void kernel_launch(void* const* d_in, const int* in_sizes, int n_in,
                              void* d_out, int out_size, void* d_ws, size_t ws_size,
                              hipStream_t stream)
{
    const float* embs   = reinterpret_cast<const float*>(d_in[0]);
    const int*   labels = reinterpret_cast<const int*>(d_in[1]);
    float*       out    = reinterpret_cast<float*>(d_out);

    float*        sums = reinterpret_cast<float*>(d_ws);        // 256 floats
    float*        cnts = sums + 256;                             // 256 floats
    unsigned int* ctr  = reinterpret_cast<unsigned int*>(cnts + 256);

    triplet_one<<<256, 256, 0, stream>>>(embs, labels, sums, cnts, ctr, out);
}

// Round 9
// 25.581 us; speedup vs baseline: 1.1017x; 1.1017x over previous
//
#include <hip/hip_runtime.h>

// BatchAllTripletLoss, B=512, E=128, labels in [0,64), MARGIN=1.0, EPS=1e-16.
// Node 1 tile_hinge (256 blocks = 16x16 grid of 32x32 anchor x negative tiles):
//   stage At/Bt/labels -> norms (8 lanes/row, all waves) -> per-anchor positive
//   masks via ballots -> plist/offs/pairRI -> posd via 16-lane coalesced
//   gathers (batch-4) -> dot-form 2x2 register dist tile -> hinge vs LDS pd ->
//   block reduce -> PLAIN store of per-block partials (no atomics, no fences).
// Node 2 finalize (1 block): reduce 256 partials, write out[0].
// Deterministic everywhere (fixed order tree reductions).

#define BSZ 512
#define EDIM 128
#define TS 32
#define NPOS 40

__global__ __launch_bounds__(256) void tile_hinge(
    const float* __restrict__ embs,
    const int* __restrict__ labels,
    float* __restrict__ sums,
    float* __restrict__ cnts)
{
    __shared__ float At[TS][EDIM + 4];
    __shared__ float Bt[TS][EDIM + 4];
    __shared__ float nA[TS], nB[TS];
    __shared__ int   lab[BSZ];
    __shared__ unsigned long long masks[TS][8];
    __shared__ int   plist[TS][NPOS];
    __shared__ float pd[TS][NPOS];
    __shared__ int   npsh[TS];
    __shared__ int   offs[TS + 1];
    __shared__ int   pairRI[TS * NPOS];
    __shared__ float wsum[4];
    __shared__ int   wcnt[4];

    const int tid = threadIdx.x;
    const int bi = blockIdx.x >> 4, bj = blockIdx.x & 15;
    const int I = bi * TS, J = bj * TS;
    const int wv = tid >> 6, lane = tid & 63;

    // ---- stage tiles + labels (coalesced float4) ----
#pragma unroll
    for (int q = 0; q < 4; ++q) {
        int idx = tid + 256 * q;
        int r = idx >> 5, k4 = idx & 31;
        float4 va = reinterpret_cast<const float4*>(embs + (size_t)(I + r) * EDIM)[k4];
        *reinterpret_cast<float4*>(&At[r][k4 * 4]) = va;
        float4 vb = reinterpret_cast<const float4*>(embs + (size_t)(J + r) * EDIM)[k4];
        *reinterpret_cast<float4*>(&Bt[r][k4 * 4]) = vb;
    }
    lab[tid]       = labels[tid];
    lab[tid + 256] = labels[tid + 256];
    __syncthreads();

    // ---- norms: 8 threads per row, all 4 waves busy ----
    {
        const int g = tid >> 3, h = tid & 7;   // row 0..31, chunk 0..7
        float s = 0.f;
#pragma unroll
        for (int k = 0; k < 4; ++k) {
            float4 v = *reinterpret_cast<float4*>(&At[g][h * 16 + k * 4]);
            s += v.x * v.x + v.y * v.y + v.z * v.z + v.w * v.w;
        }
        s += __shfl_xor(s, 1); s += __shfl_xor(s, 2); s += __shfl_xor(s, 4);
        if (h == 0) nA[g] = s;
        float t = 0.f;
#pragma unroll
        for (int k = 0; k < 4; ++k) {
            float4 v = *reinterpret_cast<float4*>(&Bt[g][h * 16 + k * 4]);
            t += v.x * v.x + v.y * v.y + v.z * v.z + v.w * v.w;
        }
        t += __shfl_xor(t, 1); t += __shfl_xor(t, 2); t += __shfl_xor(t, 4);
        if (h == 0) nB[g] = t;
    }

    // ---- per-anchor positive masks (ballots over LDS labels) ----
#pragma unroll
    for (int rr = 0; rr < 8; ++rr) {
        int r = wv * 8 + rr;
        int la = lab[I + r];
#pragma unroll
        for (int c = 0; c < 8; ++c) {
            int j = c * 64 + lane;
            unsigned long long m = __ballot(lab[j] == la && j != I + r);
            if (lane == 0) masks[r][c] = m;
        }
    }
    __syncthreads();

    // ---- positive lists (32 parallel walks) ----
    if (tid < TS) {
        int cp = 0;
#pragma unroll
        for (int w = 0; w < 8; ++w) {
            unsigned long long m = masks[tid][w];
            while (m) {
                int b = __builtin_ctzll(m);
                m &= m - 1;
                if (cp < NPOS) plist[tid][cp] = w * 64 + b;
                ++cp;
            }
        }
        npsh[tid] = cp < NPOS ? cp : NPOS;
    }
    __syncthreads();
    if (tid < TS) {
        int o = 0;
        for (int r = 0; r < tid; ++r) o += npsh[r];
        offs[tid] = o;
        if (tid == TS - 1) offs[TS] = o + npsh[tid];
        for (int i = 0; i < npsh[tid]; ++i) pairRI[o + i] = (tid << 16) | i;
    }
    __syncthreads();
    const int total = offs[TS];

    // ---- posd: 16 lanes per (a,p) pair, coalesced 512B reads, batch-4 ----
    {
        const int g = lane >> 4, lg = lane & 15;
        const float4* EB = reinterpret_cast<const float4*>(embs);
        const int q0 = wv * 4 + g;
        for (int qb = q0; qb < total; qb += 64) {
            float4 xpv[4][2];
            int rr_[4], ii_[4];
#pragma unroll
            for (int t = 0; t < 4; ++t) {
                int q = qb + t * 16;
                if (q < total) {
                    int ri = pairRI[q];
                    int r = ri >> 16, idx = ri & 0xffff;
                    rr_[t] = r; ii_[t] = idx;
                    const float4* P = EB + (size_t)plist[r][idx] * (EDIM / 4);
                    xpv[t][0] = P[lg * 2];
                    xpv[t][1] = P[lg * 2 + 1];
                } else {
                    rr_[t] = -1; ii_[t] = 0;
                    xpv[t][0] = make_float4(0.f, 0.f, 0.f, 0.f);
                    xpv[t][1] = make_float4(0.f, 0.f, 0.f, 0.f);
                }
            }
#pragma unroll
            for (int t = 0; t < 4; ++t) {
                if (rr_[t] >= 0) {
                    int r = rr_[t], idx = ii_[t];
                    float4 xa0 = *reinterpret_cast<float4*>(&At[r][lg * 8]);
                    float4 xa1 = *reinterpret_cast<float4*>(&At[r][lg * 8 + 4]);
                    float u, acc = 0.f;
                    u = xa0.x - xpv[t][0].x; acc = fmaf(u, u, acc);
                    u = xa0.y - xpv[t][0].y; acc = fmaf(u, u, acc);
                    u = xa0.z - xpv[t][0].z; acc = fmaf(u, u, acc);
                    u = xa0.w - xpv[t][0].w; acc = fmaf(u, u, acc);
                    u = xa1.x - xpv[t][1].x; acc = fmaf(u, u, acc);
                    u = xa1.y - xpv[t][1].y; acc = fmaf(u, u, acc);
                    u = xa1.z - xpv[t][1].z; acc = fmaf(u, u, acc);
                    u = xa1.w - xpv[t][1].w; acc = fmaf(u, u, acc);
                    acc += __shfl_xor(acc, 1);
                    acc += __shfl_xor(acc, 2);
                    acc += __shfl_xor(acc, 4);
                    acc += __shfl_xor(acc, 8);
                    if (lg == 0) pd[r][idx] = acc;
                }
            }
        }
    }

    // ---- dot-form 2x2 register dist tile (pure LDS, runs while pd settles) ----
    const int tr = tid >> 4, tc = tid & 15;
    float a00 = 0.f, a01 = 0.f, a10 = 0.f, a11 = 0.f;
#pragma unroll 8
    for (int k = 0; k < EDIM; k += 4) {
        float4 x0 = *reinterpret_cast<float4*>(&At[tr][k]);
        float4 x1 = *reinterpret_cast<float4*>(&At[tr + 16][k]);
        float4 y0 = *reinterpret_cast<float4*>(&Bt[tc][k]);
        float4 y1 = *reinterpret_cast<float4*>(&Bt[tc + 16][k]);
        a00 += x0.x * y0.x + x0.y * y0.y + x0.z * y0.z + x0.w * y0.w;
        a01 += x0.x * y1.x + x0.y * y1.y + x0.z * y1.z + x0.w * y1.w;
        a10 += x1.x * y0.x + x1.y * y0.y + x1.z * y0.z + x1.w * y0.w;
        a11 += x1.x * y1.x + x1.y * y1.y + x1.z * y1.z + x1.w * y1.w;
    }
    __syncthreads();   // pd + norms ready
    const float d00 = fmaxf(nA[tr]      + nB[tc]      - 2.f * a00, 0.f);
    const float d01 = fmaxf(nA[tr]      + nB[tc + 16] - 2.f * a01, 0.f);
    const float d10 = fmaxf(nA[tr + 16] + nB[tc]      - 2.f * a10, 0.f);
    const float d11 = fmaxf(nA[tr + 16] + nB[tc + 16] - 2.f * a11, 0.f);

    // ---- hinge vs LDS pd (broadcast reads) ----
    const int la0 = lab[I + tr], la1 = lab[I + tr + 16];
    const int lj0 = lab[J + tc], lj1 = lab[J + tc + 16];
    const int np0 = npsh[tr],    np1 = npsh[tr + 16];

    float s = 0.f;
    int   c = 0;
    if (lj0 != la0) for (int i = 0; i < np0; ++i) { float t = fmaxf(pd[tr][i] - d00 + 1.0f, 0.f); s += t; c += (t > 1e-16f); }
    if (lj1 != la0) for (int i = 0; i < np0; ++i) { float t = fmaxf(pd[tr][i] - d01 + 1.0f, 0.f); s += t; c += (t > 1e-16f); }
    if (lj0 != la1) for (int i = 0; i < np1; ++i) { float t = fmaxf(pd[tr + 16][i] - d10 + 1.0f, 0.f); s += t; c += (t > 1e-16f); }
    if (lj1 != la1) for (int i = 0; i < np1; ++i) { float t = fmaxf(pd[tr + 16][i] - d11 + 1.0f, 0.f); s += t; c += (t > 1e-16f); }

    // ---- block reduction + plain store ----
#pragma unroll
    for (int off = 32; off; off >>= 1) {
        s += __shfl_down(s, off);
        c += __shfl_down(c, off);
    }
    if (lane == 0) { wsum[wv] = s; wcnt[wv] = c; }
    __syncthreads();
    if (tid == 0) {
        sums[blockIdx.x] = wsum[0] + wsum[1] + wsum[2] + wsum[3];
        cnts[blockIdx.x] = (float)(wcnt[0] + wcnt[1] + wcnt[2] + wcnt[3]);
    }
}

__global__ __launch_bounds__(256) void finalize(
    const float* __restrict__ sums,
    const float* __restrict__ cnts,
    float* __restrict__ out)
{
    __shared__ float fsum[4], fcnt[4];
    const int tid = threadIdx.x;
    float s = sums[tid];
    float c = cnts[tid];
#pragma unroll
    for (int off = 32; off; off >>= 1) {
        s += __shfl_down(s, off);
        c += __shfl_down(c, off);
    }
    const int wv = tid >> 6, lane = tid & 63;
    if (lane == 0) { fsum[wv] = s; fcnt[wv] = c; }
    __syncthreads();
    if (tid == 0) {
        float S = fsum[0] + fsum[1] + fsum[2] + fsum[3];
        float C = fcnt[0] + fcnt[1] + fcnt[2] + fcnt[3];
        out[0] = S / (C + 1e-16f);
    }
}

extern "C" void kernel_launch(void* const* d_in, const int* in_sizes, int n_in,
                              void* d_out, int out_size, void* d_ws, size_t ws_size,
                              hipStream_t stream)
{
    const float* embs   = reinterpret_cast<const float*>(d_in[0]);
    const int*   labels = reinterpret_cast<const int*>(d_in[1]);
    float*       out    = reinterpret_cast<float*>(d_out);

    float* sums = reinterpret_cast<float*>(d_ws);   // 256 floats
    float* cnts = sums + 256;                        // 256 floats

    tile_hinge<<<256, 256, 0, stream>>>(embs, labels, sums, cnts);
    finalize<<<1, 256, 0, stream>>>(sums, cnts, out);
}

// Round 10
// 15.775 us; speedup vs baseline: 1.7864x; 1.6216x over previous
//
#include <hip/hip_runtime.h>
#include <hip/hip_bf16.h>

// BatchAllTripletLoss, B=512, E=128, labels in [0,64), MARGIN=1.0, EPS=1e-16.
// K1 dist_mfma:  D[i][j] = max(n_i + n_j - 2 e_i.e_j, 0) via bf16 MFMA.
//                256 blocks (16x16 grid of 32x32 tiles). Stage converts fp32
//                embs -> bf16 LDS (B-tile pre-scaled by -2, exact), computes
//                exact fp32 row norms via shfl in the same pass. Each of 4
//                waves does one 16x16 quadrant: acc init = nA[row]+nB[col]
//                (C layout: col=lane&15, row=(lane>>4)*4+reg), then 4x
//                mfma_f32_16x16x32_bf16 over K=128.
// K2 triplet_pass: unchanged from the proven 16.3us version.
// K3 finalize:   unchanged.
// No atomics anywhere -> deterministic.

#define BSZ 512
#define EDIM 128
#define TS 32
#define NPOSMAX 96

typedef __attribute__((ext_vector_type(8))) short short8;
typedef __attribute__((ext_vector_type(4))) float f32x4;

__device__ __forceinline__ unsigned short f2bf(float f) {
    __hip_bfloat16 h = __float2bfloat16(f);
    return *reinterpret_cast<unsigned short*>(&h);
}

__global__ __launch_bounds__(256) void dist_mfma(
    const float* __restrict__ embs,
    float* __restrict__ D)
{
    __shared__ unsigned short Abf[TS][136];   // bf16, +16B pad per row
    __shared__ unsigned short Bbf[TS][136];   // holds -2*b in bf16 (exact scale)
    __shared__ float nA[TS], nB[TS];

    const int tid = threadIdx.x;
    const int bi = blockIdx.x >> 4;
    const int bj = blockIdx.x & 15;
    const int I = bi * TS, J = bj * TS;
    const int wv = tid >> 6, lane = tid & 63;

    const float4* E4 = reinterpret_cast<const float4*>(embs);

    // ---- stage fp32 -> bf16 LDS + exact fp32 norms (shfl over 32-lane row groups) ----
#pragma unroll
    for (int q = 0; q < 4; ++q) {
        int idx = tid + 256 * q;      // 0..1023
        int r   = idx >> 5;           // row 0..31 (same r for 32 consecutive tids)
        int k4  = idx & 31;           // float4 index within row

        float4 va = E4[(size_t)(I + r) * (EDIM / 4) + k4];
        float sa = va.x * va.x + va.y * va.y + va.z * va.z + va.w * va.w;
        sa += __shfl_xor(sa, 1); sa += __shfl_xor(sa, 2); sa += __shfl_xor(sa, 4);
        sa += __shfl_xor(sa, 8); sa += __shfl_xor(sa, 16);
        if ((tid & 31) == 0) nA[r] = sa;
        ushort4 ua = { f2bf(va.x), f2bf(va.y), f2bf(va.z), f2bf(va.w) };
        *reinterpret_cast<ushort4*>(&Abf[r][k4 * 4]) = ua;

        float4 vb = E4[(size_t)(J + r) * (EDIM / 4) + k4];
        float sb = vb.x * vb.x + vb.y * vb.y + vb.z * vb.z + vb.w * vb.w;
        sb += __shfl_xor(sb, 1); sb += __shfl_xor(sb, 2); sb += __shfl_xor(sb, 4);
        sb += __shfl_xor(sb, 8); sb += __shfl_xor(sb, 16);
        if ((tid & 31) == 0) nB[r] = sb;
        ushort4 ub = { f2bf(-2.f * vb.x), f2bf(-2.f * vb.y),
                       f2bf(-2.f * vb.z), f2bf(-2.f * vb.w) };
        *reinterpret_cast<ushort4*>(&Bbf[r][k4 * 4]) = ub;
    }
    __syncthreads();

    // ---- MFMA: wave wv -> quadrant (qi,qj); acc init = nA[row]+nB[col] ----
    const int qi = wv >> 1, qj = wv & 1;
    const int l15 = lane & 15, lk = lane >> 4;

    f32x4 acc;
#pragma unroll
    for (int reg = 0; reg < 4; ++reg)
        acc[reg] = nA[qi * 16 + lk * 4 + reg] + nB[qj * 16 + l15];

    const unsigned short* arow = &Abf[qi * 16 + l15][0];
    const unsigned short* brow = &Bbf[qj * 16 + l15][0];
#pragma unroll
    for (int ks = 0; ks < 4; ++ks) {
        short8 af = *reinterpret_cast<const short8*>(arow + ks * 32 + lk * 8);
        short8 bf = *reinterpret_cast<const short8*>(brow + ks * 32 + lk * 8);
        acc = __builtin_amdgcn_mfma_f32_16x16x32_bf16(af, bf, acc, 0, 0, 0);
    }

    // ---- store D tile (clamped) ----
#pragma unroll
    for (int reg = 0; reg < 4; ++reg) {
        int row = I + qi * 16 + lk * 4 + reg;
        int col = J + qj * 16 + l15;
        D[(size_t)row * BSZ + col] = fmaxf(acc[reg], 0.f);
    }
}

__global__ __launch_bounds__(256) void triplet_pass(
    const float* __restrict__ D,
    const int* __restrict__ labels,
    float* __restrict__ sums,
    float* __restrict__ cnts)
{
    __shared__ int   lab[BSZ];
    __shared__ float d[BSZ];
    __shared__ unsigned long long masks[8];
    __shared__ int   plist[NPOSMAX];
    __shared__ float wsum[4];
    __shared__ int   wcnt[4];

    const int a = blockIdx.x, tid = threadIdx.x;
    const int wv = tid >> 6, lane = tid & 63;

    lab[tid]       = labels[tid];
    lab[tid + 256] = labels[tid + 256];
    float2 dv = reinterpret_cast<const float2*>(D + (size_t)a * BSZ)[tid];
    d[tid * 2]     = dv.x;
    d[tid * 2 + 1] = dv.y;
    __syncthreads();

    const int la = lab[a];

#pragma unroll
    for (int c = 0; c < 2; ++c) {
        int j = c * 256 + tid;
        unsigned long long m = __ballot(lab[j] == la && j != a);
        if (lane == 0) masks[c * 4 + wv] = m;
    }
    __syncthreads();

    int np = 0;
#pragma unroll
    for (int m = 0; m < 8; ++m) np += __popcll(masks[m]);
    if (np > NPOSMAX) np = NPOSMAX;

#pragma unroll
    for (int c = 0; c < 2; ++c) {
        int j = c * 256 + tid;
        if (lab[j] == la && j != a) {
            int mi = c * 4 + wv, off = 0;
            for (int m = 0; m < mi; ++m) off += __popcll(masks[m]);
            off += __popcll(masks[mi] & ((1ull << lane) - 1ull));
            if (off < NPOSMAX) plist[off] = j;
        }
    }
    __syncthreads();

    float s = 0.f;
    int   cnt = 0;
#pragma unroll
    for (int c = 0; c < 2; ++c) {
        int n = c * 256 + tid;
        if (lab[n] != la) {
            float dn = d[n];
            for (int i = 0; i < np; ++i) {
                float t = fmaxf(d[plist[i]] - dn + 1.0f, 0.f);
                s += t;
                cnt += (t > 1e-16f) ? 1 : 0;
            }
        }
    }

#pragma unroll
    for (int off = 32; off; off >>= 1) {
        s   += __shfl_down(s, off);
        cnt += __shfl_down(cnt, off);
    }
    if (lane == 0) { wsum[wv] = s; wcnt[wv] = cnt; }
    __syncthreads();
    if (tid == 0) {
        sums[a] = wsum[0] + wsum[1] + wsum[2] + wsum[3];
        cnts[a] = (float)(wcnt[0] + wcnt[1] + wcnt[2] + wcnt[3]);
    }
}

__global__ __launch_bounds__(512) void finalize(
    const float* __restrict__ sums,
    const float* __restrict__ cnts,
    float* __restrict__ out)
{
    __shared__ float wsum[8], wcnt[8];
    const int tid = threadIdx.x;
    float s = sums[tid];
    float c = cnts[tid];
#pragma unroll
    for (int off = 32; off; off >>= 1) {
        s += __shfl_down(s, off);
        c += __shfl_down(c, off);
    }
    const int wv = tid >> 6, lane = tid & 63;
    if (lane == 0) { wsum[wv] = s; wcnt[wv] = c; }
    __syncthreads();
    if (tid == 0) {
        float S = 0.f, C = 0.f;
#pragma unroll
        for (int w = 0; w < 8; ++w) { S += wsum[w]; C += wcnt[w]; }
        out[0] = S / (C + 1e-16f);
    }
}

extern "C" void kernel_launch(void* const* d_in, const int* in_sizes, int n_in,
                              void* d_out, int out_size, void* d_ws, size_t ws_size,
                              hipStream_t stream)
{
    const float* embs   = reinterpret_cast<const float*>(d_in[0]);
    const int*   labels = reinterpret_cast<const int*>(d_in[1]);
    float*       out    = reinterpret_cast<float*>(d_out);

    float* D    = reinterpret_cast<float*>(d_ws);                 // 1 MB
    float* sums = D + (size_t)BSZ * BSZ;                          // 2 KB
    float* cnts = sums + BSZ;                                     // 2 KB

    dist_mfma<<<256, 256, 0, stream>>>(embs, D);
    triplet_pass<<<BSZ, 256, 0, stream>>>(D, labels, sums, cnts);
    finalize<<<1, 512, 0, stream>>>(sums, cnts, out);
}